// Round 1
// baseline (4052.238 us; speedup 1.0000x reference)
//
#include <hip/hip_runtime.h>
#include <math.h>

#define IN_DIM 512
#define HG 64
#define OUT_DIM 20

__device__ __forceinline__ float selu_f(float x) {
    const float a = 1.6732632423543772f;
    const float s = 1.0507009873554805f;
    return x > 0.f ? s * x : s * a * expm1f(x);
}

// ---------------- setup kernels ----------------

__global__ void k_init(float* deg, int* cnt, int n) {
    int i = blockIdx.x * 256 + threadIdx.x;
    if (i < n) { deg[i] = 1.0f; cnt[i] = 0; }   // self-loop weight 1
}

__global__ void k_edgedeg(const int* __restrict__ ei, const float* __restrict__ ea,
                          float* deg, int* cnt, int E) {
    int e = blockIdx.x * 256 + threadIdx.x;
    if (e >= E) return;
    int c = ei[E + e];
    atomicAdd(&deg[c], ea[e]);
    atomicAdd(&cnt[c], 1);
}

__global__ void k_rsqrt(float* deg, int n) {
    int i = blockIdx.x * 256 + threadIdx.x;
    if (i < n) { float d = deg[i]; deg[i] = d > 0.f ? 1.0f / sqrtf(d) : 0.f; }
}

// block-level exclusive scan helper (256 or 512 threads)
__device__ __forceinline__ int block_excl_scan(int v, int tid, int* wsum, int nw, int* total_out) {
    int lane = tid & 63, wv = tid >> 6;
    int incl = v;
    #pragma unroll
    for (int s = 1; s < 64; s <<= 1) {
        int t = __shfl_up(incl, s, 64);
        if (lane >= s) incl += t;
    }
    if (lane == 63) wsum[wv] = incl;
    __syncthreads();
    int prefix = 0;
    for (int i = 0; i < wv; i++) prefix += wsum[i];
    int total = 0;
    for (int i = 0; i < nw; i++) total += wsum[i];
    *total_out = total;
    return prefix + incl - v;
}

__global__ void k_scan1(const int* __restrict__ cnt, int* __restrict__ offar,
                        int* __restrict__ blockSums, int n) {
    __shared__ int wsum[4];
    int i = blockIdx.x * 256 + threadIdx.x;
    int v = (i < n) ? cnt[i] : 0;
    int total;
    int excl = block_excl_scan(v, threadIdx.x, wsum, 4, &total);
    if (i < n) offar[i] = excl;
    if (threadIdx.x == 0) blockSums[blockIdx.x] = total;
}

__global__ void k_scan2(const int* __restrict__ blockSums, int* __restrict__ blockOffs, int nb) {
    __shared__ int wsum[8];
    int v = (threadIdx.x < nb) ? blockSums[threadIdx.x] : 0;
    int total;
    int excl = block_excl_scan(v, threadIdx.x, wsum, 8, &total);
    if (threadIdx.x < nb) blockOffs[threadIdx.x] = excl;
}

__global__ void k_scan3(int* __restrict__ offar, const int* __restrict__ blockOffs,
                        int* __restrict__ cursor, int n, int E) {
    int i = blockIdx.x * 256 + threadIdx.x;
    if (i < n) {
        int o = offar[i] + blockOffs[blockIdx.x];
        offar[i] = o;
        cursor[i] = o;
    }
    if (i == 0) offar[n] = E;
}

__global__ void k_scatter(const int* __restrict__ ei, const float* __restrict__ ea,
                          const float* __restrict__ dinv, int* cursor,
                          int* __restrict__ srcA, float* __restrict__ valA, int E) {
    int e = blockIdx.x * 256 + threadIdx.x;
    if (e >= E) return;
    int r = ei[e], c = ei[E + e];
    int pos = atomicAdd(&cursor[c], 1);
    srcA[pos] = r;
    valA[pos] = dinv[r] * ea[e] * dinv[c];
}

// ---------------- GEMM: [n,KTOT] x [KTOT,64] -> [n,64], optional bias+selu ----------------

template <int KTOT, bool BIAS, bool ACT>
__global__ __launch_bounds__(256) void k_gemm(const float* __restrict__ A, const float* __restrict__ W,
                                              const float* __restrict__ bias, float* __restrict__ out, int n) {
    __shared__ float xs[128][65];
    __shared__ float ws[64][64];
    const int t = threadIdx.x;
    const int r0 = blockIdx.x * 128;
    const int tc = t & 7;    // 8 cols per thread
    const int tr = t >> 3;   // 0..31, 4 rows per thread
    float acc[4][8];
    #pragma unroll
    for (int i = 0; i < 4; i++)
        #pragma unroll
        for (int j = 0; j < 8; j++) acc[i][j] = 0.f;

    #pragma unroll 1
    for (int k0 = 0; k0 < KTOT; k0 += 64) {
        // stage A tile: 128 rows x 64 k
        #pragma unroll
        for (int l = 0; l < 8; l++) {
            int flat = t + l * 256;      // 0..2047 float4s
            int row = flat >> 4, c4 = flat & 15;
            int gr = r0 + row;
            float4 v = make_float4(0.f, 0.f, 0.f, 0.f);
            if (gr < n) v = *reinterpret_cast<const float4*>(&A[(size_t)gr * KTOT + k0 + c4 * 4]);
            xs[row][c4 * 4 + 0] = v.x; xs[row][c4 * 4 + 1] = v.y;
            xs[row][c4 * 4 + 2] = v.z; xs[row][c4 * 4 + 3] = v.w;
        }
        // stage W tile: 64 k x 64 cols
        #pragma unroll
        for (int l = 0; l < 4; l++) {
            int flat = t + l * 256;      // 0..1023 float4s
            int row = flat >> 4, c4 = flat & 15;
            *reinterpret_cast<float4*>(&ws[row][c4 * 4]) =
                *reinterpret_cast<const float4*>(&W[(size_t)(k0 + row) * 64 + c4 * 4]);
        }
        __syncthreads();
        #pragma unroll
        for (int kk = 0; kk < 64; ++kk) {
            float4 w0 = *reinterpret_cast<const float4*>(&ws[kk][tc * 8]);
            float4 w1 = *reinterpret_cast<const float4*>(&ws[kk][tc * 8 + 4]);
            #pragma unroll
            for (int i = 0; i < 4; i++) {
                float xv = xs[tr * 4 + i][kk];
                acc[i][0] += xv * w0.x; acc[i][1] += xv * w0.y;
                acc[i][2] += xv * w0.z; acc[i][3] += xv * w0.w;
                acc[i][4] += xv * w1.x; acc[i][5] += xv * w1.y;
                acc[i][6] += xv * w1.z; acc[i][7] += xv * w1.w;
            }
        }
        __syncthreads();
    }
    float bv[8];
    #pragma unroll
    for (int j = 0; j < 8; j++) bv[j] = BIAS ? bias[tc * 8 + j] : 0.f;
    #pragma unroll
    for (int i = 0; i < 4; i++) {
        int gr = r0 + tr * 4 + i;
        if (gr < n) {
            float o[8];
            #pragma unroll
            for (int j = 0; j < 8; j++) {
                float v2 = acc[i][j] + bv[j];
                o[j] = ACT ? selu_f(v2) : v2;
            }
            *reinterpret_cast<float4*>(&out[(size_t)gr * 64 + tc * 8]) = make_float4(o[0], o[1], o[2], o[3]);
            *reinterpret_cast<float4*>(&out[(size_t)gr * 64 + tc * 8 + 4]) = make_float4(o[4], o[5], o[6], o[7]);
        }
    }
}

// ---------------- CSR gather-aggregate + bias + selu (one wave per node) ----------------

__global__ __launch_bounds__(256) void k_agg(const float* __restrict__ xw, const float* __restrict__ dinv,
                                             const int* __restrict__ off, const int* __restrict__ srcA,
                                             const float* __restrict__ valA, const float* __restrict__ bias,
                                             float* __restrict__ out, int n) {
    int node = (blockIdx.x * 256 + threadIdx.x) >> 6;
    int lane = threadIdx.x & 63;
    if (node >= n) return;
    float d = dinv[node];
    float acc = d * d * xw[(size_t)node * 64 + lane];   // self-loop
    int p0 = off[node], p1 = off[node + 1];
    for (int p = p0; p < p1; ++p) {
        int s = srcA[p];
        float v = valA[p];
        acc += v * xw[(size_t)s * 64 + lane];
    }
    out[(size_t)node * 64 + lane] = selu_f(acc + bias[lane]);
}

// ---------------- final layer [n,64]x[64,20] + softmax ----------------

__global__ __launch_bounds__(256) void k_lin3soft(const float* __restrict__ A, const float* __restrict__ W3,
                                                  const float* __restrict__ b3, float* __restrict__ out, int n) {
    __shared__ float xs[128][65];
    __shared__ float ws[64][32];
    const int t = threadIdx.x;
    const int r0 = blockIdx.x * 128;
    const int tc = t & 7;    // 4 cols per thread over 32 padded cols
    const int tr = t >> 3;   // 4 rows per thread

    #pragma unroll
    for (int l = 0; l < 8; l++) {
        int flat = t + l * 256;
        int row = flat >> 4, c4 = flat & 15;
        int gr = r0 + row;
        float4 v = make_float4(0.f, 0.f, 0.f, 0.f);
        if (gr < n) v = *reinterpret_cast<const float4*>(&A[(size_t)gr * 64 + c4 * 4]);
        xs[row][c4 * 4 + 0] = v.x; xs[row][c4 * 4 + 1] = v.y;
        xs[row][c4 * 4 + 2] = v.z; xs[row][c4 * 4 + 3] = v.w;
    }
    for (int l = t; l < 64 * 32; l += 256) {
        int row = l >> 5, c = l & 31;
        ws[row][c] = (c < OUT_DIM) ? W3[row * OUT_DIM + c] : 0.f;
    }
    __syncthreads();

    float acc[4][4];
    #pragma unroll
    for (int i = 0; i < 4; i++)
        #pragma unroll
        for (int j = 0; j < 4; j++) acc[i][j] = 0.f;

    #pragma unroll
    for (int kk = 0; kk < 64; ++kk) {
        float4 wv = *reinterpret_cast<const float4*>(&ws[kk][tc * 4]);
        #pragma unroll
        for (int i = 0; i < 4; i++) {
            float xv = xs[tr * 4 + i][kk];
            acc[i][0] += xv * wv.x; acc[i][1] += xv * wv.y;
            acc[i][2] += xv * wv.z; acc[i][3] += xv * wv.w;
        }
    }

    float bv[4];
    #pragma unroll
    for (int j = 0; j < 4; j++) {
        int c = tc * 4 + j;
        bv[j] = (c < OUT_DIM) ? b3[c] : 0.f;
    }
    #pragma unroll
    for (int i = 0; i < 4; i++) {
        int gr = r0 + tr * 4 + i;
        float l4[4];
        #pragma unroll
        for (int j = 0; j < 4; j++) {
            int c = tc * 4 + j;
            l4[j] = (c < OUT_DIM) ? (acc[i][j] + bv[j]) : -INFINITY;
        }
        float m = fmaxf(fmaxf(l4[0], l4[1]), fmaxf(l4[2], l4[3]));
        m = fmaxf(m, __shfl_xor(m, 1));
        m = fmaxf(m, __shfl_xor(m, 2));
        m = fmaxf(m, __shfl_xor(m, 4));
        float e[4]; float s = 0.f;
        #pragma unroll
        for (int j = 0; j < 4; j++) {
            int c = tc * 4 + j;
            e[j] = (c < OUT_DIM) ? expf(l4[j] - m) : 0.f;
            s += e[j];
        }
        s += __shfl_xor(s, 1);
        s += __shfl_xor(s, 2);
        s += __shfl_xor(s, 4);
        float inv = 1.0f / s;
        if (gr < n && tc < 5) {
            *reinterpret_cast<float4*>(&out[(size_t)gr * OUT_DIM + tc * 4]) =
                make_float4(e[0] * inv, e[1] * inv, e[2] * inv, e[3] * inv);
        }
    }
}

// ---------------- launcher ----------------

extern "C" void kernel_launch(void* const* d_in, const int* in_sizes, int n_in,
                              void* d_out, int out_size, void* d_ws, size_t ws_size,
                              hipStream_t stream) {
    const float* x     = (const float*)d_in[0];
    const int*   ei    = (const int*)d_in[1];
    const float* ea    = (const float*)d_in[2];
    const float* gc0_w = (const float*)d_in[3];
    const float* gc0_b = (const float*)d_in[4];
    const float* gc1_w = (const float*)d_in[5];
    const float* gc1_b = (const float*)d_in[6];
    const float* lin0_w = (const float*)d_in[7];
    const float* lin0_b = (const float*)d_in[8];
    const float* lin1_w = (const float*)d_in[9];
    const float* lin1_b = (const float*)d_in[10];
    const float* lin2_w = (const float*)d_in[11];
    const float* lin2_b = (const float*)d_in[12];
    const float* lin3_w = (const float*)d_in[13];
    const float* lin3_b = (const float*)d_in[14];
    float* out = (float*)d_out;

    const int N = in_sizes[0] / IN_DIM;    // 100000
    const int E = in_sizes[2];             // 1600000
    const int nb1 = (N + 255) / 256;       // scan blocks

    // workspace layout (256B aligned chunks)
    char* w = (char*)d_ws;
    auto alloc = [&](size_t bytes) { char* p = w; w += (bytes + 255) & ~(size_t)255; return p; };
    float* dinv      = (float*)alloc((size_t)N * 4);
    int*   cnt       = (int*)alloc((size_t)N * 4);
    int*   offar     = (int*)alloc((size_t)(N + 1) * 4);
    int*   cursor    = (int*)alloc((size_t)N * 4);
    int*   blockSums = (int*)alloc((size_t)nb1 * 4);
    int*   blockOffs = (int*)alloc((size_t)nb1 * 4);
    int*   srcA      = (int*)alloc((size_t)E * 4);
    float* valA      = (float*)alloc((size_t)E * 4);
    float* bufA      = (float*)alloc((size_t)N * 64 * 4);
    float* bufB      = (float*)alloc((size_t)N * 64 * 4);

    const int gN  = (N + 255) / 256;
    const int gE  = (E + 255) / 256;
    const int gT  = (N + 127) / 128;   // gemm tiles
    const int gA  = (N + 3) / 4;       // aggregate: 4 waves/block

    k_init<<<gN, 256, 0, stream>>>(dinv, cnt, N);
    k_edgedeg<<<gE, 256, 0, stream>>>(ei, ea, dinv, cnt, E);
    k_rsqrt<<<gN, 256, 0, stream>>>(dinv, N);
    k_scan1<<<nb1, 256, 0, stream>>>(cnt, offar, blockSums, N);
    k_scan2<<<1, 512, 0, stream>>>(blockSums, blockOffs, nb1);
    k_scan3<<<nb1, 256, 0, stream>>>(offar, blockOffs, cursor, N, E);
    k_scatter<<<gE, 256, 0, stream>>>(ei, ea, dinv, cursor, srcA, valA, E);

    // conv0: xw = x @ W0 ; h0 = selu(agg(xw) + b0)
    k_gemm<IN_DIM, false, false><<<gT, 256, 0, stream>>>(x, gc0_w, nullptr, bufA, N);
    k_agg<<<gA, 256, 0, stream>>>(bufA, dinv, offar, srcA, valA, gc0_b, bufB, N);
    // conv1
    k_gemm<HG, false, false><<<gT, 256, 0, stream>>>(bufB, gc1_w, nullptr, bufA, N);
    k_agg<<<gA, 256, 0, stream>>>(bufA, dinv, offar, srcA, valA, gc1_b, bufB, N);
    // dense stack
    k_gemm<HG, true, true><<<gT, 256, 0, stream>>>(bufB, lin0_w, lin0_b, bufA, N);
    k_gemm<HG, true, true><<<gT, 256, 0, stream>>>(bufA, lin1_w, lin1_b, bufB, N);
    k_gemm<HG, true, true><<<gT, 256, 0, stream>>>(bufB, lin2_w, lin2_b, bufA, N);
    k_lin3soft<<<gT, 256, 0, stream>>>(bufA, lin3_w, lin3_b, out, N);
}

// Round 2
// 1111.136 us; speedup vs baseline: 3.6469x; 3.6469x over previous
//
#include <hip/hip_runtime.h>
#include <math.h>

#define IN_DIM 512
#define HG 64
#define OUT_DIM 20

__device__ __forceinline__ float selu_f(float x) {
    const float a = 1.6732632423543772f;
    const float s = 1.0507009873554805f;
    return x > 0.f ? s * x : s * a * expm1f(x);
}

// ---------------- setup kernels ----------------

__global__ void k_init(float* deg, int* cnt, int n) {
    int i = blockIdx.x * 256 + threadIdx.x;
    if (i < n) { deg[i] = 1.0f; cnt[i] = 0; }   // self-loop weight 1
}

__global__ void k_edgedeg(const int* __restrict__ ei, const float* __restrict__ ea,
                          float* deg, int* cnt, int E) {
    int e = blockIdx.x * 256 + threadIdx.x;
    if (e >= E) return;
    int c = ei[E + e];
    atomicAdd(&deg[c], ea[e]);
    atomicAdd(&cnt[c], 1);
}

__global__ void k_rsqrt(float* deg, int n) {
    int i = blockIdx.x * 256 + threadIdx.x;
    if (i < n) { float d = deg[i]; deg[i] = d > 0.f ? 1.0f / sqrtf(d) : 0.f; }
}

// block-level exclusive scan helper (256 or 512 threads)
__device__ __forceinline__ int block_excl_scan(int v, int tid, int* wsum, int nw, int* total_out) {
    int lane = tid & 63, wv = tid >> 6;
    int incl = v;
    #pragma unroll
    for (int s = 1; s < 64; s <<= 1) {
        int t = __shfl_up(incl, s, 64);
        if (lane >= s) incl += t;
    }
    if (lane == 63) wsum[wv] = incl;
    __syncthreads();
    int prefix = 0;
    for (int i = 0; i < wv; i++) prefix += wsum[i];
    int total = 0;
    for (int i = 0; i < nw; i++) total += wsum[i];
    *total_out = total;
    return prefix + incl - v;
}

__global__ void k_scan1(const int* __restrict__ cnt, int* __restrict__ offar,
                        int* __restrict__ blockSums, int n) {
    __shared__ int wsum[4];
    int i = blockIdx.x * 256 + threadIdx.x;
    int v = (i < n) ? cnt[i] : 0;
    int total;
    int excl = block_excl_scan(v, threadIdx.x, wsum, 4, &total);
    if (i < n) offar[i] = excl;
    if (threadIdx.x == 0) blockSums[blockIdx.x] = total;
}

__global__ void k_scan2(const int* __restrict__ blockSums, int* __restrict__ blockOffs, int nb) {
    __shared__ int wsum[8];
    int v = (threadIdx.x < nb) ? blockSums[threadIdx.x] : 0;
    int total;
    int excl = block_excl_scan(v, threadIdx.x, wsum, 8, &total);
    if (threadIdx.x < nb) blockOffs[threadIdx.x] = excl;
}

__global__ void k_scan3(int* __restrict__ offar, const int* __restrict__ blockOffs,
                        int* __restrict__ cursor, int n, int E) {
    int i = blockIdx.x * 256 + threadIdx.x;
    if (i < n) {
        int o = offar[i] + blockOffs[blockIdx.x];
        offar[i] = o;
        cursor[i] = o;
    }
    if (i == 0) offar[n] = E;
}

__global__ void k_scatter(const int* __restrict__ ei, const float* __restrict__ ea,
                          const float* __restrict__ dinv, int* cursor,
                          int* __restrict__ srcA, float* __restrict__ valA, int E) {
    int e = blockIdx.x * 256 + threadIdx.x;
    if (e >= E) return;
    int r = ei[e], c = ei[E + e];
    int pos = atomicAdd(&cursor[c], 1);
    srcA[pos] = r;
    valA[pos] = dinv[r] * ea[e] * dinv[c];
}

// ---------------- GEMM: [n,KTOT] x [KTOT,64] -> [n,64], optional bias+selu ----------------
// launch_bounds(256,4): cap at 128 VGPR/wave. Round-1 profile showed VGPR=256
// (cap) + 1.26GB fetch / 243MB write of scratch spill traffic -> 946us.
// Inner unroll limited to 8 to keep the live window ~70 VGPRs.

template <int KTOT, bool BIAS, bool ACT>
__global__ __launch_bounds__(256, 4) void k_gemm(const float* __restrict__ A, const float* __restrict__ W,
                                                 const float* __restrict__ bias, float* __restrict__ out, int n) {
    __shared__ float xs[128][65];
    __shared__ float ws[64][64];
    const int t = threadIdx.x;
    const int r0 = blockIdx.x * 128;
    const int tc = t & 7;    // 8 cols per thread
    const int tr = t >> 3;   // 0..31, 4 rows per thread
    float acc[4][8];
    #pragma unroll
    for (int i = 0; i < 4; i++)
        #pragma unroll
        for (int j = 0; j < 8; j++) acc[i][j] = 0.f;

    #pragma unroll 1
    for (int k0 = 0; k0 < KTOT; k0 += 64) {
        // stage A tile: 128 rows x 64 k
        #pragma unroll
        for (int l = 0; l < 8; l++) {
            int flat = t + l * 256;      // 0..2047 float4s
            int row = flat >> 4, c4 = flat & 15;
            int gr = r0 + row;
            float4 v = make_float4(0.f, 0.f, 0.f, 0.f);
            if (gr < n) v = *reinterpret_cast<const float4*>(&A[(size_t)gr * KTOT + k0 + c4 * 4]);
            xs[row][c4 * 4 + 0] = v.x; xs[row][c4 * 4 + 1] = v.y;
            xs[row][c4 * 4 + 2] = v.z; xs[row][c4 * 4 + 3] = v.w;
        }
        // stage W tile: 64 k x 64 cols
        #pragma unroll
        for (int l = 0; l < 4; l++) {
            int flat = t + l * 256;      // 0..1023 float4s
            int row = flat >> 4, c4 = flat & 15;
            *reinterpret_cast<float4*>(&ws[row][c4 * 4]) =
                *reinterpret_cast<const float4*>(&W[(size_t)(k0 + row) * 64 + c4 * 4]);
        }
        __syncthreads();
        #pragma unroll 8
        for (int kk = 0; kk < 64; ++kk) {
            float4 w0 = *reinterpret_cast<const float4*>(&ws[kk][tc * 8]);
            float4 w1 = *reinterpret_cast<const float4*>(&ws[kk][tc * 8 + 4]);
            #pragma unroll
            for (int i = 0; i < 4; i++) {
                float xv = xs[tr * 4 + i][kk];
                acc[i][0] += xv * w0.x; acc[i][1] += xv * w0.y;
                acc[i][2] += xv * w0.z; acc[i][3] += xv * w0.w;
                acc[i][4] += xv * w1.x; acc[i][5] += xv * w1.y;
                acc[i][6] += xv * w1.z; acc[i][7] += xv * w1.w;
            }
        }
        __syncthreads();
    }
    float bv[8];
    #pragma unroll
    for (int j = 0; j < 8; j++) bv[j] = BIAS ? bias[tc * 8 + j] : 0.f;
    #pragma unroll
    for (int i = 0; i < 4; i++) {
        int gr = r0 + tr * 4 + i;
        if (gr < n) {
            float o[8];
            #pragma unroll
            for (int j = 0; j < 8; j++) {
                float v2 = acc[i][j] + bv[j];
                o[j] = ACT ? selu_f(v2) : v2;
            }
            *reinterpret_cast<float4*>(&out[(size_t)gr * 64 + tc * 8]) = make_float4(o[0], o[1], o[2], o[3]);
            *reinterpret_cast<float4*>(&out[(size_t)gr * 64 + tc * 8 + 4]) = make_float4(o[4], o[5], o[6], o[7]);
        }
    }
}

// ---------------- CSR gather-aggregate + bias + selu (one wave per node) ----------------

__global__ __launch_bounds__(256) void k_agg(const float* __restrict__ xw, const float* __restrict__ dinv,
                                             const int* __restrict__ off, const int* __restrict__ srcA,
                                             const float* __restrict__ valA, const float* __restrict__ bias,
                                             float* __restrict__ out, int n) {
    int node = (blockIdx.x * 256 + threadIdx.x) >> 6;
    int lane = threadIdx.x & 63;
    if (node >= n) return;
    float d = dinv[node];
    float acc = d * d * xw[(size_t)node * 64 + lane];   // self-loop
    int p0 = off[node], p1 = off[node + 1];
    for (int p = p0; p < p1; ++p) {
        int s = srcA[p];
        float v = valA[p];
        acc += v * xw[(size_t)s * 64 + lane];
    }
    out[(size_t)node * 64 + lane] = selu_f(acc + bias[lane]);
}

// ---------------- final layer [n,64]x[64,20] + softmax ----------------

__global__ __launch_bounds__(256, 4) void k_lin3soft(const float* __restrict__ A, const float* __restrict__ W3,
                                                     const float* __restrict__ b3, float* __restrict__ out, int n) {
    __shared__ float xs[128][65];
    __shared__ float ws[64][32];
    const int t = threadIdx.x;
    const int r0 = blockIdx.x * 128;
    const int tc = t & 7;    // 4 cols per thread over 32 padded cols
    const int tr = t >> 3;   // 4 rows per thread

    #pragma unroll
    for (int l = 0; l < 8; l++) {
        int flat = t + l * 256;
        int row = flat >> 4, c4 = flat & 15;
        int gr = r0 + row;
        float4 v = make_float4(0.f, 0.f, 0.f, 0.f);
        if (gr < n) v = *reinterpret_cast<const float4*>(&A[(size_t)gr * 64 + c4 * 4]);
        xs[row][c4 * 4 + 0] = v.x; xs[row][c4 * 4 + 1] = v.y;
        xs[row][c4 * 4 + 2] = v.z; xs[row][c4 * 4 + 3] = v.w;
    }
    for (int l = t; l < 64 * 32; l += 256) {
        int row = l >> 5, c = l & 31;
        ws[row][c] = (c < OUT_DIM) ? W3[row * OUT_DIM + c] : 0.f;
    }
    __syncthreads();

    float acc[4][4];
    #pragma unroll
    for (int i = 0; i < 4; i++)
        #pragma unroll
        for (int j = 0; j < 4; j++) acc[i][j] = 0.f;

    #pragma unroll 8
    for (int kk = 0; kk < 64; ++kk) {
        float4 wv = *reinterpret_cast<const float4*>(&ws[kk][tc * 4]);
        #pragma unroll
        for (int i = 0; i < 4; i++) {
            float xv = xs[tr * 4 + i][kk];
            acc[i][0] += xv * wv.x; acc[i][1] += xv * wv.y;
            acc[i][2] += xv * wv.z; acc[i][3] += xv * wv.w;
        }
    }

    float bv[4];
    #pragma unroll
    for (int j = 0; j < 4; j++) {
        int c = tc * 4 + j;
        bv[j] = (c < OUT_DIM) ? b3[c] : 0.f;
    }
    #pragma unroll
    for (int i = 0; i < 4; i++) {
        int gr = r0 + tr * 4 + i;
        float l4[4];
        #pragma unroll
        for (int j = 0; j < 4; j++) {
            int c = tc * 4 + j;
            l4[j] = (c < OUT_DIM) ? (acc[i][j] + bv[j]) : -INFINITY;
        }
        float m = fmaxf(fmaxf(l4[0], l4[1]), fmaxf(l4[2], l4[3]));
        m = fmaxf(m, __shfl_xor(m, 1));
        m = fmaxf(m, __shfl_xor(m, 2));
        m = fmaxf(m, __shfl_xor(m, 4));
        float e[4]; float s = 0.f;
        #pragma unroll
        for (int j = 0; j < 4; j++) {
            int c = tc * 4 + j;
            e[j] = (c < OUT_DIM) ? expf(l4[j] - m) : 0.f;
            s += e[j];
        }
        s += __shfl_xor(s, 1);
        s += __shfl_xor(s, 2);
        s += __shfl_xor(s, 4);
        float inv = 1.0f / s;
        if (gr < n && tc < 5) {
            *reinterpret_cast<float4*>(&out[(size_t)gr * OUT_DIM + tc * 4]) =
                make_float4(e[0] * inv, e[1] * inv, e[2] * inv, e[3] * inv);
        }
    }
}

// ---------------- launcher ----------------

extern "C" void kernel_launch(void* const* d_in, const int* in_sizes, int n_in,
                              void* d_out, int out_size, void* d_ws, size_t ws_size,
                              hipStream_t stream) {
    const float* x     = (const float*)d_in[0];
    const int*   ei    = (const int*)d_in[1];
    const float* ea    = (const float*)d_in[2];
    const float* gc0_w = (const float*)d_in[3];
    const float* gc0_b = (const float*)d_in[4];
    const float* gc1_w = (const float*)d_in[5];
    const float* gc1_b = (const float*)d_in[6];
    const float* lin0_w = (const float*)d_in[7];
    const float* lin0_b = (const float*)d_in[8];
    const float* lin1_w = (const float*)d_in[9];
    const float* lin1_b = (const float*)d_in[10];
    const float* lin2_w = (const float*)d_in[11];
    const float* lin2_b = (const float*)d_in[12];
    const float* lin3_w = (const float*)d_in[13];
    const float* lin3_b = (const float*)d_in[14];
    float* out = (float*)d_out;

    const int N = in_sizes[0] / IN_DIM;    // 100000
    const int E = in_sizes[2];             // 1600000
    const int nb1 = (N + 255) / 256;       // scan blocks

    // workspace layout (256B aligned chunks)
    char* w = (char*)d_ws;
    auto alloc = [&](size_t bytes) { char* p = w; w += (bytes + 255) & ~(size_t)255; return p; };
    float* dinv      = (float*)alloc((size_t)N * 4);
    int*   cnt       = (int*)alloc((size_t)N * 4);
    int*   offar     = (int*)alloc((size_t)(N + 1) * 4);
    int*   cursor    = (int*)alloc((size_t)N * 4);
    int*   blockSums = (int*)alloc((size_t)nb1 * 4);
    int*   blockOffs = (int*)alloc((size_t)nb1 * 4);
    int*   srcA      = (int*)alloc((size_t)E * 4);
    float* valA      = (float*)alloc((size_t)E * 4);
    float* bufA      = (float*)alloc((size_t)N * 64 * 4);
    float* bufB      = (float*)alloc((size_t)N * 64 * 4);

    const int gN  = (N + 255) / 256;
    const int gE  = (E + 255) / 256;
    const int gT  = (N + 127) / 128;   // gemm tiles
    const int gA  = (N + 3) / 4;       // aggregate: 4 waves/block

    k_init<<<gN, 256, 0, stream>>>(dinv, cnt, N);
    k_edgedeg<<<gE, 256, 0, stream>>>(ei, ea, dinv, cnt, E);
    k_rsqrt<<<gN, 256, 0, stream>>>(dinv, N);
    k_scan1<<<nb1, 256, 0, stream>>>(cnt, offar, blockSums, N);
    k_scan2<<<1, 512, 0, stream>>>(blockSums, blockOffs, nb1);
    k_scan3<<<nb1, 256, 0, stream>>>(offar, blockOffs, cursor, N, E);
    k_scatter<<<gE, 256, 0, stream>>>(ei, ea, dinv, cursor, srcA, valA, E);

    // conv0: xw = x @ W0 ; h0 = selu(agg(xw) + b0)
    k_gemm<IN_DIM, false, false><<<gT, 256, 0, stream>>>(x, gc0_w, nullptr, bufA, N);
    k_agg<<<gA, 256, 0, stream>>>(bufA, dinv, offar, srcA, valA, gc0_b, bufB, N);
    // conv1
    k_gemm<HG, false, false><<<gT, 256, 0, stream>>>(bufB, gc1_w, nullptr, bufA, N);
    k_agg<<<gA, 256, 0, stream>>>(bufA, dinv, offar, srcA, valA, gc1_b, bufB, N);
    // dense stack
    k_gemm<HG, true, true><<<gT, 256, 0, stream>>>(bufB, lin0_w, lin0_b, bufA, N);
    k_gemm<HG, true, true><<<gT, 256, 0, stream>>>(bufA, lin1_w, lin1_b, bufB, N);
    k_gemm<HG, true, true><<<gT, 256, 0, stream>>>(bufB, lin2_w, lin2_b, bufA, N);
    k_lin3soft<<<gT, 256, 0, stream>>>(bufA, lin3_w, lin3_b, out, N);
}

// Round 3
// 1013.353 us; speedup vs baseline: 3.9988x; 1.0965x over previous
//
#include <hip/hip_runtime.h>
#include <math.h>

#define IN_DIM 512
#define HG 64
#define OUT_DIM 20

typedef __attribute__((ext_vector_type(8))) short bf16x8;
typedef __attribute__((ext_vector_type(4))) float f32x4;

__device__ __forceinline__ float selu_f(float x) {
    const float a = 1.6732632423543772f;
    const float s = 1.0507009873554805f;
    return x > 0.f ? s * x : s * a * expm1f(x);
}

// fp32 -> bf16 round-to-nearest-even (data is finite; no NaN guard needed)
__device__ __forceinline__ unsigned short f2bf(float f) {
    unsigned int u = __float_as_uint(f);
    u += 0x7FFFu + ((u >> 16) & 1u);
    return (unsigned short)(u >> 16);
}
__device__ __forceinline__ float bf2f(unsigned short b) {
    return __uint_as_float(((unsigned int)b) << 16);
}

// ---------------- setup kernels ----------------

__global__ void k_init(float* deg, int* cnt, int n) {
    int i = blockIdx.x * 256 + threadIdx.x;
    if (i < n) { deg[i] = 1.0f; cnt[i] = 0; }   // self-loop weight 1
}

__global__ void k_edgedeg(const int* __restrict__ ei, const float* __restrict__ ea,
                          float* deg, int* cnt, int E) {
    int e = blockIdx.x * 256 + threadIdx.x;
    if (e >= E) return;
    int c = ei[E + e];
    atomicAdd(&deg[c], ea[e]);
    atomicAdd(&cnt[c], 1);
}

__global__ void k_rsqrt(float* deg, int n) {
    int i = blockIdx.x * 256 + threadIdx.x;
    if (i < n) { float d = deg[i]; deg[i] = d > 0.f ? 1.0f / sqrtf(d) : 0.f; }
}

__device__ __forceinline__ int block_excl_scan(int v, int tid, int* wsum, int nw, int* total_out) {
    int lane = tid & 63, wv = tid >> 6;
    int incl = v;
    #pragma unroll
    for (int s = 1; s < 64; s <<= 1) {
        int t = __shfl_up(incl, s, 64);
        if (lane >= s) incl += t;
    }
    if (lane == 63) wsum[wv] = incl;
    __syncthreads();
    int prefix = 0;
    for (int i = 0; i < wv; i++) prefix += wsum[i];
    int total = 0;
    for (int i = 0; i < nw; i++) total += wsum[i];
    *total_out = total;
    return prefix + incl - v;
}

__global__ void k_scan1(const int* __restrict__ cnt, int* __restrict__ offar,
                        int* __restrict__ blockSums, int n) {
    __shared__ int wsum[4];
    int i = blockIdx.x * 256 + threadIdx.x;
    int v = (i < n) ? cnt[i] : 0;
    int total;
    int excl = block_excl_scan(v, threadIdx.x, wsum, 4, &total);
    if (i < n) offar[i] = excl;
    if (threadIdx.x == 0) blockSums[blockIdx.x] = total;
}

__global__ void k_scan2(const int* __restrict__ blockSums, int* __restrict__ blockOffs, int nb) {
    __shared__ int wsum[8];
    int v = (threadIdx.x < nb) ? blockSums[threadIdx.x] : 0;
    int total;
    int excl = block_excl_scan(v, threadIdx.x, wsum, 8, &total);
    if (threadIdx.x < nb) blockOffs[threadIdx.x] = excl;
}

__global__ void k_scan3(int* __restrict__ offar, const int* __restrict__ blockOffs,
                        int* __restrict__ cursor, int n, int E) {
    int i = blockIdx.x * 256 + threadIdx.x;
    if (i < n) {
        int o = offar[i] + blockOffs[blockIdx.x];
        offar[i] = o;
        cursor[i] = o;
    }
    if (i == 0) offar[n] = E;
}

__global__ void k_scatter(const int* __restrict__ ei, const float* __restrict__ ea,
                          const float* __restrict__ dinv, int* cursor,
                          int* __restrict__ srcA, float* __restrict__ valA, int E) {
    int e = blockIdx.x * 256 + threadIdx.x;
    if (e >= E) return;
    int r = ei[e], c = ei[E + e];
    int pos = atomicAdd(&cursor[c], 1);
    srcA[pos] = r;
    valA[pos] = dinv[r] * ea[e] * dinv[c];
}

// ---------------- weight split: W[K][C] fp32 -> WT_hi/WT_lo [Cpad][K] bf16 ----------------

__global__ void k_splitw(const float* __restrict__ W, unsigned short* __restrict__ hi,
                         unsigned short* __restrict__ lo, int K, int C, int Cpad) {
    int i = blockIdx.x * 256 + threadIdx.x;
    if (i >= Cpad * K) return;
    int c = i / K, k = i - c * K;
    float wv = (c < C) ? W[(size_t)k * C + c] : 0.f;
    unsigned short h = f2bf(wv);
    hi[i] = h;
    lo[i] = f2bf(wv - bf2f(h));
}

// ---------------- MFMA GEMM: [n,K] fp32 x WT_hi/lo -> [n,64] fp32 ----------------
// bf16 hi/lo split, 3-product (hiHi + hiLo + loHi), fp32 accumulate.
// No LDS. Block = 4 waves x 32 rows = 128 rows. Per wave: 2 row-tiles x 4 col-tiles.
// A/B fragments use the SAME slot->k bijection (k = k0 + 8*(lane>>4) + j), so the
// contraction is exact regardless of the HW canonical k order. C/D layout (verified
// m89): col = lane&15, row = 4*(lane>>4) + reg.

template <int K, bool BIAS, bool ACT>
__global__ __launch_bounds__(256, 3)
void k_gemm_mfma(const float* __restrict__ A, const unsigned short* __restrict__ WThi,
                 const unsigned short* __restrict__ WTlo, const float* __restrict__ bias,
                 float* __restrict__ out, int n) {
    const int t = threadIdx.x;
    const int lane = t & 63;
    const int w = t >> 6;
    const int l15 = lane & 15;
    const int g = lane >> 4;
    const int r0 = blockIdx.x * 128 + w * 32;
    if (r0 >= n) return;   // n % 32 == 0 for this problem; no barriers in kernel

    f32x4 acc[2][4];
    #pragma unroll
    for (int rt = 0; rt < 2; rt++)
        #pragma unroll
        for (int ct = 0; ct < 4; ct++) acc[rt][ct] = (f32x4)0.f;

    #pragma unroll 1
    for (int k0 = 0; k0 < K; k0 += 32) {
        bf16x8 bh[4], bl[4];
        #pragma unroll
        for (int ct = 0; ct < 4; ct++) {
            size_t off = (size_t)(ct * 16 + l15) * K + k0 + 8 * g;
            bh[ct] = *(const bf16x8*)(WThi + off);
            bl[ct] = *(const bf16x8*)(WTlo + off);
        }
        #pragma unroll
        for (int rt = 0; rt < 2; rt++) {
            const float* ap = A + (size_t)(r0 + rt * 16 + l15) * K + k0 + 8 * g;
            float4 v0 = *(const float4*)(ap);
            float4 v1 = *(const float4*)(ap + 4);
            float vv[8] = {v0.x, v0.y, v0.z, v0.w, v1.x, v1.y, v1.z, v1.w};
            bf16x8 ah, al;
            #pragma unroll
            for (int j = 0; j < 8; j++) {
                unsigned short h = f2bf(vv[j]);
                ah[j] = (short)h;
                al[j] = (short)f2bf(vv[j] - bf2f(h));
            }
            #pragma unroll
            for (int ct = 0; ct < 4; ct++) {
                acc[rt][ct] = __builtin_amdgcn_mfma_f32_16x16x32_bf16(ah, bh[ct], acc[rt][ct], 0, 0, 0);
                acc[rt][ct] = __builtin_amdgcn_mfma_f32_16x16x32_bf16(ah, bl[ct], acc[rt][ct], 0, 0, 0);
                acc[rt][ct] = __builtin_amdgcn_mfma_f32_16x16x32_bf16(al, bh[ct], acc[rt][ct], 0, 0, 0);
            }
        }
    }

    float bv[4];
    #pragma unroll
    for (int ct = 0; ct < 4; ct++) bv[ct] = BIAS ? bias[ct * 16 + l15] : 0.f;

    #pragma unroll
    for (int rt = 0; rt < 2; rt++) {
        #pragma unroll
        for (int r = 0; r < 4; r++) {
            int gr = r0 + rt * 16 + 4 * g + r;
            #pragma unroll
            for (int ct = 0; ct < 4; ct++) {
                float v = acc[rt][ct][r] + bv[ct];
                if (ACT) v = selu_f(v);
                out[(size_t)gr * 64 + ct * 16 + l15] = v;
            }
        }
    }
}

// ---------------- final layer MFMA [n,64]x[64,20] + softmax epilogue ----------------

__global__ __launch_bounds__(256, 3)
void k_lin3s(const float* __restrict__ A, const unsigned short* __restrict__ WThi,
             const unsigned short* __restrict__ WTlo, const float* __restrict__ b3,
             float* __restrict__ out, int n) {
    const int t = threadIdx.x;
    const int lane = t & 63;
    const int w = t >> 6;
    const int l15 = lane & 15;
    const int g = lane >> 4;
    const int r0 = blockIdx.x * 128 + w * 32;
    if (r0 >= n) return;

    f32x4 acc[2][2];
    #pragma unroll
    for (int rt = 0; rt < 2; rt++)
        #pragma unroll
        for (int ct = 0; ct < 2; ct++) acc[rt][ct] = (f32x4)0.f;

    #pragma unroll 1
    for (int k0 = 0; k0 < 64; k0 += 32) {
        bf16x8 bh[2], bl[2];
        #pragma unroll
        for (int ct = 0; ct < 2; ct++) {
            size_t off = (size_t)(ct * 16 + l15) * 64 + k0 + 8 * g;
            bh[ct] = *(const bf16x8*)(WThi + off);
            bl[ct] = *(const bf16x8*)(WTlo + off);
        }
        #pragma unroll
        for (int rt = 0; rt < 2; rt++) {
            const float* ap = A + (size_t)(r0 + rt * 16 + l15) * 64 + k0 + 8 * g;
            float4 v0 = *(const float4*)(ap);
            float4 v1 = *(const float4*)(ap + 4);
            float vv[8] = {v0.x, v0.y, v0.z, v0.w, v1.x, v1.y, v1.z, v1.w};
            bf16x8 ah, al;
            #pragma unroll
            for (int j = 0; j < 8; j++) {
                unsigned short h = f2bf(vv[j]);
                ah[j] = (short)h;
                al[j] = (short)f2bf(vv[j] - bf2f(h));
            }
            #pragma unroll
            for (int ct = 0; ct < 2; ct++) {
                acc[rt][ct] = __builtin_amdgcn_mfma_f32_16x16x32_bf16(ah, bh[ct], acc[rt][ct], 0, 0, 0);
                acc[rt][ct] = __builtin_amdgcn_mfma_f32_16x16x32_bf16(ah, bl[ct], acc[rt][ct], 0, 0, 0);
                acc[rt][ct] = __builtin_amdgcn_mfma_f32_16x16x32_bf16(al, bh[ct], acc[rt][ct], 0, 0, 0);
            }
        }
    }

    float b0v = b3[l15];
    float b1v = (l15 < 4) ? b3[16 + l15] : 0.f;

    #pragma unroll
    for (int rt = 0; rt < 2; rt++) {
        #pragma unroll
        for (int r = 0; r < 4; r++) {
            int gr = r0 + rt * 16 + 4 * g + r;
            float v0 = acc[rt][0][r] + b0v;                         // cols 0..15
            float v1 = (l15 < 4) ? acc[rt][1][r] + b1v : -INFINITY; // cols 16..19
            float mx = fmaxf(v0, v1);
            mx = fmaxf(mx, __shfl_xor(mx, 1));
            mx = fmaxf(mx, __shfl_xor(mx, 2));
            mx = fmaxf(mx, __shfl_xor(mx, 4));
            mx = fmaxf(mx, __shfl_xor(mx, 8));
            float e0 = expf(v0 - mx);
            float e1 = (l15 < 4) ? expf(v1 - mx) : 0.f;
            float s = e0 + e1;
            s += __shfl_xor(s, 1);
            s += __shfl_xor(s, 2);
            s += __shfl_xor(s, 4);
            s += __shfl_xor(s, 8);
            float inv = 1.0f / s;
            out[(size_t)gr * OUT_DIM + l15] = e0 * inv;
            if (l15 < 4) out[(size_t)gr * OUT_DIM + 16 + l15] = e1 * inv;
        }
    }
}

// ---------------- CSR gather-aggregate + bias + selu (one wave per node) ----------------

__global__ __launch_bounds__(256) void k_agg(const float* __restrict__ xw, const float* __restrict__ dinv,
                                             const int* __restrict__ off, const int* __restrict__ srcA,
                                             const float* __restrict__ valA, const float* __restrict__ bias,
                                             float* __restrict__ out, int n) {
    int node = (blockIdx.x * 256 + threadIdx.x) >> 6;
    int lane = threadIdx.x & 63;
    if (node >= n) return;
    float d = dinv[node];
    float acc = d * d * xw[(size_t)node * 64 + lane];   // self-loop
    int p0 = off[node], p1 = off[node + 1];
    for (int p = p0; p < p1; ++p) {
        int s = srcA[p];
        float v = valA[p];
        acc += v * xw[(size_t)s * 64 + lane];
    }
    out[(size_t)node * 64 + lane] = selu_f(acc + bias[lane]);
}

// ---------------- launcher ----------------

extern "C" void kernel_launch(void* const* d_in, const int* in_sizes, int n_in,
                              void* d_out, int out_size, void* d_ws, size_t ws_size,
                              hipStream_t stream) {
    const float* x     = (const float*)d_in[0];
    const int*   ei    = (const int*)d_in[1];
    const float* ea    = (const float*)d_in[2];
    const float* gc0_w = (const float*)d_in[3];
    const float* gc0_b = (const float*)d_in[4];
    const float* gc1_w = (const float*)d_in[5];
    const float* gc1_b = (const float*)d_in[6];
    const float* lin0_w = (const float*)d_in[7];
    const float* lin0_b = (const float*)d_in[8];
    const float* lin1_w = (const float*)d_in[9];
    const float* lin1_b = (const float*)d_in[10];
    const float* lin2_w = (const float*)d_in[11];
    const float* lin2_b = (const float*)d_in[12];
    const float* lin3_w = (const float*)d_in[13];
    const float* lin3_b = (const float*)d_in[14];
    float* out = (float*)d_out;

    const int N = in_sizes[0] / IN_DIM;    // 100000
    const int E = in_sizes[2];             // 1600000
    const int nb1 = (N + 255) / 256;

    char* w = (char*)d_ws;
    auto alloc = [&](size_t bytes) { char* p = w; w += (bytes + 255) & ~(size_t)255; return p; };
    float* dinv      = (float*)alloc((size_t)N * 4);
    int*   cnt       = (int*)alloc((size_t)N * 4);
    int*   offar     = (int*)alloc((size_t)(N + 1) * 4);
    int*   cursor    = (int*)alloc((size_t)N * 4);
    int*   blockSums = (int*)alloc((size_t)nb1 * 4);
    int*   blockOffs = (int*)alloc((size_t)nb1 * 4);
    int*   srcA      = (int*)alloc((size_t)E * 4);
    float* valA      = (float*)alloc((size_t)E * 4);
    float* bufA      = (float*)alloc((size_t)N * 64 * 4);
    float* bufB      = (float*)alloc((size_t)N * 64 * 4);
    // split/transposed weights (bf16)
    unsigned short* wt0h = (unsigned short*)alloc(64 * 512 * 2);
    unsigned short* wt0l = (unsigned short*)alloc(64 * 512 * 2);
    unsigned short* wt1h = (unsigned short*)alloc(64 * 64 * 2);
    unsigned short* wt1l = (unsigned short*)alloc(64 * 64 * 2);
    unsigned short* wl0h = (unsigned short*)alloc(64 * 64 * 2);
    unsigned short* wl0l = (unsigned short*)alloc(64 * 64 * 2);
    unsigned short* wl1h = (unsigned short*)alloc(64 * 64 * 2);
    unsigned short* wl1l = (unsigned short*)alloc(64 * 64 * 2);
    unsigned short* wl2h = (unsigned short*)alloc(64 * 64 * 2);
    unsigned short* wl2l = (unsigned short*)alloc(64 * 64 * 2);
    unsigned short* wt3h = (unsigned short*)alloc(32 * 64 * 2);
    unsigned short* wt3l = (unsigned short*)alloc(32 * 64 * 2);

    const int gN = (N + 255) / 256;
    const int gE = (E + 255) / 256;
    const int gT = (N + 127) / 128;
    const int gA = (N + 3) / 4;

    k_init<<<gN, 256, 0, stream>>>(dinv, cnt, N);
    k_edgedeg<<<gE, 256, 0, stream>>>(ei, ea, dinv, cnt, E);
    k_rsqrt<<<gN, 256, 0, stream>>>(dinv, N);
    k_scan1<<<nb1, 256, 0, stream>>>(cnt, offar, blockSums, N);
    k_scan2<<<1, 512, 0, stream>>>(blockSums, blockOffs, nb1);
    k_scan3<<<nb1, 256, 0, stream>>>(offar, blockOffs, cursor, N, E);
    k_scatter<<<gE, 256, 0, stream>>>(ei, ea, dinv, cursor, srcA, valA, E);

    k_splitw<<<128, 256, 0, stream>>>(gc0_w, wt0h, wt0l, 512, 64, 64);
    k_splitw<<<16, 256, 0, stream>>>(gc1_w, wt1h, wt1l, 64, 64, 64);
    k_splitw<<<16, 256, 0, stream>>>(lin0_w, wl0h, wl0l, 64, 64, 64);
    k_splitw<<<16, 256, 0, stream>>>(lin1_w, wl1h, wl1l, 64, 64, 64);
    k_splitw<<<16, 256, 0, stream>>>(lin2_w, wl2h, wl2l, 64, 64, 64);
    k_splitw<<<8, 256, 0, stream>>>(lin3_w, wt3h, wt3l, 64, OUT_DIM, 32);

    // conv0
    k_gemm_mfma<IN_DIM, false, false><<<gT, 256, 0, stream>>>(x, wt0h, wt0l, nullptr, bufA, N);
    k_agg<<<gA, 256, 0, stream>>>(bufA, dinv, offar, srcA, valA, gc0_b, bufB, N);
    // conv1
    k_gemm_mfma<HG, false, false><<<gT, 256, 0, stream>>>(bufB, wt1h, wt1l, nullptr, bufA, N);
    k_agg<<<gA, 256, 0, stream>>>(bufA, dinv, offar, srcA, valA, gc1_b, bufB, N);
    // dense stack
    k_gemm_mfma<HG, true, true><<<gT, 256, 0, stream>>>(bufB, wl0h, wl0l, lin0_b, bufA, N);
    k_gemm_mfma<HG, true, true><<<gT, 256, 0, stream>>>(bufA, wl1h, wl1l, lin1_b, bufB, N);
    k_gemm_mfma<HG, true, true><<<gT, 256, 0, stream>>>(bufB, wl2h, wl2l, lin2_b, bufA, N);
    k_lin3s<<<gT, 256, 0, stream>>>(bufA, wt3h, wt3l, lin3_b, out, N);
}

// Round 4
// 833.659 us; speedup vs baseline: 4.8608x; 1.2155x over previous
//
#include <hip/hip_runtime.h>
#include <math.h>

#define IN_DIM 512
#define HG 64
#define OUT_DIM 20

typedef __attribute__((ext_vector_type(8))) short bf16x8;
typedef __attribute__((ext_vector_type(4))) short bf16x4;
typedef __attribute__((ext_vector_type(4))) float f32x4;

__device__ __forceinline__ float selu_f(float x) {
    const float a = 1.6732632423543772f;
    const float s = 1.0507009873554805f;
    return x > 0.f ? s * x : s * a * expm1f(x);
}

// fp32 -> bf16 round-to-nearest-even (data finite; no NaN guard needed)
__device__ __forceinline__ unsigned short f2bf(float f) {
    unsigned int u = __float_as_uint(f);
    u += 0x7FFFu + ((u >> 16) & 1u);
    return (unsigned short)(u >> 16);
}
__device__ __forceinline__ float bf2f(unsigned short b) {
    return __uint_as_float(((unsigned int)b) << 16);
}

// ---------------- setup kernels ----------------

__global__ void k_init(float* deg, int* cnt, int n) {
    int i = blockIdx.x * 256 + threadIdx.x;
    if (i < n) { deg[i] = 1.0f; cnt[i] = 0; }   // self-loop weight 1
}

__global__ void k_edgedeg(const int* __restrict__ ei, const float* __restrict__ ea,
                          float* deg, int* cnt, int E) {
    int e = blockIdx.x * 256 + threadIdx.x;
    if (e >= E) return;
    int c = ei[E + e];
    atomicAdd(&deg[c], ea[e]);
    atomicAdd(&cnt[c], 1);
}

__global__ void k_rsqrt(float* deg, int n) {
    int i = blockIdx.x * 256 + threadIdx.x;
    if (i < n) { float d = deg[i]; deg[i] = d > 0.f ? 1.0f / sqrtf(d) : 0.f; }
}

__device__ __forceinline__ int block_excl_scan(int v, int tid, int* wsum, int nw, int* total_out) {
    int lane = tid & 63, wv = tid >> 6;
    int incl = v;
    #pragma unroll
    for (int s = 1; s < 64; s <<= 1) {
        int t = __shfl_up(incl, s, 64);
        if (lane >= s) incl += t;
    }
    if (lane == 63) wsum[wv] = incl;
    __syncthreads();
    int prefix = 0;
    for (int i = 0; i < wv; i++) prefix += wsum[i];
    int total = 0;
    for (int i = 0; i < nw; i++) total += wsum[i];
    *total_out = total;
    return prefix + incl - v;
}

__global__ void k_scan1(const int* __restrict__ cnt, int* __restrict__ offar,
                        int* __restrict__ blockSums, int n) {
    __shared__ int wsum[4];
    int i = blockIdx.x * 256 + threadIdx.x;
    int v = (i < n) ? cnt[i] : 0;
    int total;
    int excl = block_excl_scan(v, threadIdx.x, wsum, 4, &total);
    if (i < n) offar[i] = excl;
    if (threadIdx.x == 0) blockSums[blockIdx.x] = total;
}

__global__ void k_scan2(const int* __restrict__ blockSums, int* __restrict__ blockOffs, int nb) {
    __shared__ int wsum[8];
    int v = (threadIdx.x < nb) ? blockSums[threadIdx.x] : 0;
    int total;
    int excl = block_excl_scan(v, threadIdx.x, wsum, 8, &total);
    if (threadIdx.x < nb) blockOffs[threadIdx.x] = excl;
}

__global__ void k_scan3(int* __restrict__ offar, const int* __restrict__ blockOffs,
                        int* __restrict__ cursor, int n, int E) {
    int i = blockIdx.x * 256 + threadIdx.x;
    if (i < n) {
        int o = offar[i] + blockOffs[blockIdx.x];
        offar[i] = o;
        cursor[i] = o;
    }
    if (i == 0) offar[n] = E;
}

__global__ void k_scatter(const int* __restrict__ ei, const float* __restrict__ ea,
                          const float* __restrict__ dinv, int* cursor,
                          int* __restrict__ srcA, float* __restrict__ valA, int E) {
    int e = blockIdx.x * 256 + threadIdx.x;
    if (e >= E) return;
    int r = ei[e], c = ei[E + e];
    int pos = atomicAdd(&cursor[c], 1);
    srcA[pos] = r;
    valA[pos] = dinv[r] * ea[e] * dinv[c];
}

// ---------------- weight split: W[K][C] fp32 -> WT_hi/WT_lo [Cpad][K] bf16 ----------------

__global__ void k_splitw(const float* __restrict__ W, unsigned short* __restrict__ hi,
                         unsigned short* __restrict__ lo, int K, int C, int Cpad) {
    int i = blockIdx.x * 256 + threadIdx.x;
    if (i >= Cpad * K) return;
    int c = i / K, k = i - c * K;
    float wv = (c < C) ? W[(size_t)k * C + c] : 0.f;
    unsigned short h = f2bf(wv);
    hi[i] = h;
    lo[i] = f2bf(wv - bf2f(h));
}

// ---------------- MFMA GEMM (conv layers): [n,K] fp32 x WT_hi/lo -> [n,64] fp32 ----------------
// bf16 hi/lo split, 3-product, fp32 accumulate. No LDS. 4 waves x 32 rows.
// A/B share slot->k bijection (k = k0 + 8g + j). C/D: col=lane&15, row=4g+reg (m89).

template <int K, bool BIAS, bool ACT>
__global__ __launch_bounds__(256, 3)
void k_gemm_mfma(const float* __restrict__ A, const unsigned short* __restrict__ WThi,
                 const unsigned short* __restrict__ WTlo, const float* __restrict__ bias,
                 float* __restrict__ out, int n) {
    const int t = threadIdx.x;
    const int lane = t & 63;
    const int w = t >> 6;
    const int l15 = lane & 15;
    const int g = lane >> 4;
    const int r0 = blockIdx.x * 128 + w * 32;
    if (r0 >= n) return;   // N % 32 == 0; no barriers in kernel

    f32x4 acc[2][4];
    #pragma unroll
    for (int rt = 0; rt < 2; rt++)
        #pragma unroll
        for (int ct = 0; ct < 4; ct++) acc[rt][ct] = (f32x4)0.f;

    #pragma unroll 1
    for (int k0 = 0; k0 < K; k0 += 32) {
        bf16x8 bh[4], bl[4];
        #pragma unroll
        for (int ct = 0; ct < 4; ct++) {
            size_t off = (size_t)(ct * 16 + l15) * K + k0 + 8 * g;
            bh[ct] = *(const bf16x8*)(WThi + off);
            bl[ct] = *(const bf16x8*)(WTlo + off);
        }
        #pragma unroll
        for (int rt = 0; rt < 2; rt++) {
            const float* ap = A + (size_t)(r0 + rt * 16 + l15) * K + k0 + 8 * g;
            float4 v0 = *(const float4*)(ap);
            float4 v1 = *(const float4*)(ap + 4);
            float vv[8] = {v0.x, v0.y, v0.z, v0.w, v1.x, v1.y, v1.z, v1.w};
            bf16x8 ah, al;
            #pragma unroll
            for (int j = 0; j < 8; j++) {
                unsigned short h = f2bf(vv[j]);
                ah[j] = (short)h;
                al[j] = (short)f2bf(vv[j] - bf2f(h));
            }
            #pragma unroll
            for (int ct = 0; ct < 4; ct++) {
                acc[rt][ct] = __builtin_amdgcn_mfma_f32_16x16x32_bf16(ah, bh[ct], acc[rt][ct], 0, 0, 0);
                acc[rt][ct] = __builtin_amdgcn_mfma_f32_16x16x32_bf16(ah, bl[ct], acc[rt][ct], 0, 0, 0);
                acc[rt][ct] = __builtin_amdgcn_mfma_f32_16x16x32_bf16(al, bh[ct], acc[rt][ct], 0, 0, 0);
            }
        }
    }

    float bv[4];
    #pragma unroll
    for (int ct = 0; ct < 4; ct++) bv[ct] = BIAS ? bias[ct * 16 + l15] : 0.f;

    #pragma unroll
    for (int rt = 0; rt < 2; rt++) {
        #pragma unroll
        for (int r = 0; r < 4; r++) {
            int gr = r0 + rt * 16 + 4 * g + r;
            #pragma unroll
            for (int ct = 0; ct < 4; ct++) {
                float v = acc[rt][ct][r] + bv[ct];
                if (ACT) v = selu_f(v);
                out[(size_t)gr * 64 + ct * 16 + l15] = v;
            }
        }
    }
}

// ---------------- CSR gather-aggregate + bias + selu ----------------
// One wave per node; each lane owns a float2 feature pair so a HALF-wave covers
// one 256B row -> 2 edges per instruction; 4-deep unroll per half -> 8 gathers
// in flight (round-3 profile: latency-bound at 18% VALU / 18% HBM).

__global__ __launch_bounds__(256) void k_agg(const float* __restrict__ xw, const float* __restrict__ dinv,
                                             const int* __restrict__ off, const int* __restrict__ srcA,
                                             const float* __restrict__ valA, const float* __restrict__ bias,
                                             float* __restrict__ out, int n) {
    int node = (blockIdx.x * 256 + threadIdx.x) >> 6;
    int lane = threadIdx.x & 63;
    if (node >= n) return;
    const int half = lane >> 5;       // which edge-parity this half-wave handles
    const int l32 = lane & 31;        // feature pair index: feats 2*l32, 2*l32+1
    const float2* __restrict__ xw2 = (const float2*)xw;

    int p0 = off[node], p1 = off[node + 1];
    float ax = 0.f, ay = 0.f;
    int p = p0 + half;
    // 4 edges per half per iteration (stride 2 within half)
    for (; p + 6 < p1; p += 8) {
        int s0 = srcA[p];
        int s1 = srcA[p + 2];
        int s2 = srcA[p + 4];
        int s3 = srcA[p + 6];
        float v0 = valA[p], v1 = valA[p + 2], v2 = valA[p + 4], v3 = valA[p + 6];
        float2 x0 = xw2[(size_t)s0 * 32 + l32];
        float2 x1 = xw2[(size_t)s1 * 32 + l32];
        float2 x2 = xw2[(size_t)s2 * 32 + l32];
        float2 x3 = xw2[(size_t)s3 * 32 + l32];
        ax += v0 * x0.x + v1 * x1.x + v2 * x2.x + v3 * x3.x;
        ay += v0 * x0.y + v1 * x1.y + v2 * x2.y + v3 * x3.y;
    }
    for (; p < p1; p += 2) {
        int s = srcA[p];
        float v = valA[p];
        float2 xv = xw2[(size_t)s * 32 + l32];
        ax += v * xv.x;
        ay += v * xv.y;
    }
    // combine halves
    ax += __shfl_xor(ax, 32);
    ay += __shfl_xor(ay, 32);
    if (half == 0) {
        float d = dinv[node];
        float2 self = xw2[(size_t)node * 32 + l32];
        float2 o;
        o.x = selu_f(ax + d * d * self.x + bias[2 * l32]);
        o.y = selu_f(ay + d * d * self.y + bias[2 * l32 + 1]);
        ((float2*)out)[(size_t)node * 32 + l32] = o;
    }
}

// ---------------- fused dense stack: lin0..lin2 (+selu) -> lin3 -> softmax ----------------
// Transposed orientation: A-operand = W^T fragment (rows = out-features),
// B-operand = H^T fragment (cols = nodes). Slot bijection
// sigma(k0,g,j) = 32*k0 + 16*(j>>2) + 4*g + (j&3): the layer-(l) D output
// (lane l15 = node, values = out-features 16ct+4g+r) is EXACTLY the layer-(l+1)
// B-fragment under sigma -> pure register repack between layers. No LDS.

__global__ __launch_bounds__(256, 3)
void k_dense(const float* __restrict__ H,
             const unsigned short* __restrict__ w0h, const unsigned short* __restrict__ w0l, const float* __restrict__ b0,
             const unsigned short* __restrict__ w1h, const unsigned short* __restrict__ w1l, const float* __restrict__ b1,
             const unsigned short* __restrict__ w2h, const unsigned short* __restrict__ w2l, const float* __restrict__ b2,
             const unsigned short* __restrict__ w3h, const unsigned short* __restrict__ w3l, const float* __restrict__ b3,
             float* __restrict__ out, int n) {
    const int t = threadIdx.x, lane = t & 63, w = t >> 6;
    const int l15 = lane & 15, g = lane >> 4;
    const int r0 = blockIdx.x * 128 + w * 32;
    if (r0 >= n) return;   // N % 32 == 0

    // B-fragments for current layer input (hi/lo), [node-tile][k0]
    bf16x8 bh[2][2], bl[2][2];
    #pragma unroll
    for (int nt = 0; nt < 2; nt++) {
        const float* hp = H + (size_t)(r0 + nt * 16 + l15) * 64;
        #pragma unroll
        for (int k0 = 0; k0 < 2; k0++) {
            float4 c0 = *(const float4*)(hp + 32 * k0 + 4 * g);
            float4 c1 = *(const float4*)(hp + 32 * k0 + 16 + 4 * g);
            float vv[8] = {c0.x, c0.y, c0.z, c0.w, c1.x, c1.y, c1.z, c1.w};
            #pragma unroll
            for (int j = 0; j < 8; j++) {
                unsigned short hb = f2bf(vv[j]);
                bh[nt][k0][j] = (short)hb;
                bl[nt][k0][j] = (short)f2bf(vv[j] - bf2f(hb));
            }
        }
    }

    const unsigned short* whs[3] = {w0h, w1h, w2h};
    const unsigned short* wls[3] = {w0l, w1l, w2l};
    const float* bs[3] = {b0, b1, b2};

    #pragma unroll
    for (int layer = 0; layer < 3; layer++) {
        float accS[2][4][4];   // [nt][ct][r] post-activation, statically indexed
        #pragma unroll
        for (int ct = 0; ct < 4; ct++) {
            bf16x8 ah[2], al[2];
            #pragma unroll
            for (int k0 = 0; k0 < 2; k0++) {
                size_t off = (size_t)(16 * ct + l15) * 64 + 32 * k0 + 4 * g;
                bf16x4 h0 = *(const bf16x4*)(whs[layer] + off);
                bf16x4 h1 = *(const bf16x4*)(whs[layer] + off + 16);
                bf16x4 l0 = *(const bf16x4*)(wls[layer] + off);
                bf16x4 l1 = *(const bf16x4*)(wls[layer] + off + 16);
                #pragma unroll
                for (int j = 0; j < 4; j++) {
                    ah[k0][j] = h0[j]; ah[k0][4 + j] = h1[j];
                    al[k0][j] = l0[j]; al[k0][4 + j] = l1[j];
                }
            }
            float4 bv = *(const float4*)(bs[layer] + 16 * ct + 4 * g);
            float bvr[4] = {bv.x, bv.y, bv.z, bv.w};
            #pragma unroll
            for (int nt = 0; nt < 2; nt++) {
                f32x4 acc = (f32x4)0.f;
                #pragma unroll
                for (int k0 = 0; k0 < 2; k0++) {
                    acc = __builtin_amdgcn_mfma_f32_16x16x32_bf16(ah[k0], bh[nt][k0], acc, 0, 0, 0);
                    acc = __builtin_amdgcn_mfma_f32_16x16x32_bf16(ah[k0], bl[nt][k0], acc, 0, 0, 0);
                    acc = __builtin_amdgcn_mfma_f32_16x16x32_bf16(al[k0], bh[nt][k0], acc, 0, 0, 0);
                }
                #pragma unroll
                for (int r = 0; r < 4; r++) accS[nt][ct][r] = selu_f(acc[r] + bvr[r]);
            }
        }
        // repack accS -> next-layer B-fragments (feature 16ct+4g+r at slot sigma)
        #pragma unroll
        for (int nt = 0; nt < 2; nt++)
            #pragma unroll
            for (int k0 = 0; k0 < 2; k0++)
                #pragma unroll
                for (int j = 0; j < 8; j++) {
                    float v = accS[nt][2 * k0 + (j >> 2)][j & 3];
                    unsigned short hb = f2bf(v);
                    bh[nt][k0][j] = (short)hb;
                    bl[nt][k0][j] = (short)f2bf(v - bf2f(hb));
                }
    }

    // lin3 (out 20, padded 32) + softmax
    float z[2][2][4];
    #pragma unroll
    for (int ct = 0; ct < 2; ct++) {
        bf16x8 ah[2], al[2];
        #pragma unroll
        for (int k0 = 0; k0 < 2; k0++) {
            size_t off = (size_t)(16 * ct + l15) * 64 + 32 * k0 + 4 * g;
            bf16x4 h0 = *(const bf16x4*)(w3h + off);
            bf16x4 h1 = *(const bf16x4*)(w3h + off + 16);
            bf16x4 l0 = *(const bf16x4*)(w3l + off);
            bf16x4 l1 = *(const bf16x4*)(w3l + off + 16);
            #pragma unroll
            for (int j = 0; j < 4; j++) {
                ah[k0][j] = h0[j]; ah[k0][4 + j] = h1[j];
                al[k0][j] = l0[j]; al[k0][4 + j] = l1[j];
            }
        }
        #pragma unroll
        for (int nt = 0; nt < 2; nt++) {
            f32x4 acc = (f32x4)0.f;
            #pragma unroll
            for (int k0 = 0; k0 < 2; k0++) {
                acc = __builtin_amdgcn_mfma_f32_16x16x32_bf16(ah[k0], bh[nt][k0], acc, 0, 0, 0);
                acc = __builtin_amdgcn_mfma_f32_16x16x32_bf16(ah[k0], bl[nt][k0], acc, 0, 0, 0);
                acc = __builtin_amdgcn_mfma_f32_16x16x32_bf16(al[k0], bh[nt][k0], acc, 0, 0, 0);
            }
            #pragma unroll
            for (int r = 0; r < 4; r++) {
                int f = 16 * ct + 4 * g + r;
                float bb = (f < OUT_DIM) ? b3[f] : 0.f;
                z[nt][ct][r] = acc[r] + bb;
            }
        }
    }
    #pragma unroll
    for (int nt = 0; nt < 2; nt++) {
        int node = r0 + nt * 16 + l15;
        float mx = -INFINITY;
        #pragma unroll
        for (int ct = 0; ct < 2; ct++)
            #pragma unroll
            for (int r = 0; r < 4; r++) {
                if (ct == 0 || g == 0) mx = fmaxf(mx, z[nt][ct][r]);
            }
        mx = fmaxf(mx, __shfl_xor(mx, 16));
        mx = fmaxf(mx, __shfl_xor(mx, 32));
        float e[2][4];
        float s = 0.f;
        #pragma unroll
        for (int ct = 0; ct < 2; ct++)
            #pragma unroll
            for (int r = 0; r < 4; r++) {
                if (ct == 0 || g == 0) {
                    e[ct][r] = expf(z[nt][ct][r] - mx);
                    s += e[ct][r];
                } else e[ct][r] = 0.f;
            }
        s += __shfl_xor(s, 16);
        s += __shfl_xor(s, 32);
        float inv = 1.0f / s;
        #pragma unroll
        for (int ct = 0; ct < 2; ct++)
            #pragma unroll
            for (int r = 0; r < 4; r++) {
                int f = 16 * ct + 4 * g + r;
                if (ct == 0 || g == 0)
                    out[(size_t)node * OUT_DIM + f] = e[ct][r] * inv;
            }
    }
}

// ---------------- launcher ----------------

extern "C" void kernel_launch(void* const* d_in, const int* in_sizes, int n_in,
                              void* d_out, int out_size, void* d_ws, size_t ws_size,
                              hipStream_t stream) {
    const float* x     = (const float*)d_in[0];
    const int*   ei    = (const int*)d_in[1];
    const float* ea    = (const float*)d_in[2];
    const float* gc0_w = (const float*)d_in[3];
    const float* gc0_b = (const float*)d_in[4];
    const float* gc1_w = (const float*)d_in[5];
    const float* gc1_b = (const float*)d_in[6];
    const float* lin0_w = (const float*)d_in[7];
    const float* lin0_b = (const float*)d_in[8];
    const float* lin1_w = (const float*)d_in[9];
    const float* lin1_b = (const float*)d_in[10];
    const float* lin2_w = (const float*)d_in[11];
    const float* lin2_b = (const float*)d_in[12];
    const float* lin3_w = (const float*)d_in[13];
    const float* lin3_b = (const float*)d_in[14];
    float* out = (float*)d_out;

    const int N = in_sizes[0] / IN_DIM;    // 100000
    const int E = in_sizes[2];             // 1600000
    const int nb1 = (N + 255) / 256;

    char* w = (char*)d_ws;
    auto alloc = [&](size_t bytes) { char* p = w; w += (bytes + 255) & ~(size_t)255; return p; };
    float* dinv      = (float*)alloc((size_t)N * 4);
    int*   cnt       = (int*)alloc((size_t)N * 4);
    int*   offar     = (int*)alloc((size_t)(N + 1) * 4);
    int*   cursor    = (int*)alloc((size_t)N * 4);
    int*   blockSums = (int*)alloc((size_t)nb1 * 4);
    int*   blockOffs = (int*)alloc((size_t)nb1 * 4);
    int*   srcA      = (int*)alloc((size_t)E * 4);
    float* valA      = (float*)alloc((size_t)E * 4);
    float* bufA      = (float*)alloc((size_t)N * 64 * 4);
    float* bufB      = (float*)alloc((size_t)N * 64 * 4);
    unsigned short* wt0h = (unsigned short*)alloc(64 * 512 * 2);
    unsigned short* wt0l = (unsigned short*)alloc(64 * 512 * 2);
    unsigned short* wt1h = (unsigned short*)alloc(64 * 64 * 2);
    unsigned short* wt1l = (unsigned short*)alloc(64 * 64 * 2);
    unsigned short* wl0h = (unsigned short*)alloc(64 * 64 * 2);
    unsigned short* wl0l = (unsigned short*)alloc(64 * 64 * 2);
    unsigned short* wl1h = (unsigned short*)alloc(64 * 64 * 2);
    unsigned short* wl1l = (unsigned short*)alloc(64 * 64 * 2);
    unsigned short* wl2h = (unsigned short*)alloc(64 * 64 * 2);
    unsigned short* wl2l = (unsigned short*)alloc(64 * 64 * 2);
    unsigned short* wt3h = (unsigned short*)alloc(32 * 64 * 2);
    unsigned short* wt3l = (unsigned short*)alloc(32 * 64 * 2);

    const int gN = (N + 255) / 256;
    const int gE = (E + 255) / 256;
    const int gT = (N + 127) / 128;
    const int gA = (N + 3) / 4;

    k_init<<<gN, 256, 0, stream>>>(dinv, cnt, N);
    k_edgedeg<<<gE, 256, 0, stream>>>(ei, ea, dinv, cnt, E);
    k_rsqrt<<<gN, 256, 0, stream>>>(dinv, N);
    k_scan1<<<nb1, 256, 0, stream>>>(cnt, offar, blockSums, N);
    k_scan2<<<1, 512, 0, stream>>>(blockSums, blockOffs, nb1);
    k_scan3<<<nb1, 256, 0, stream>>>(offar, blockOffs, cursor, N, E);
    k_scatter<<<gE, 256, 0, stream>>>(ei, ea, dinv, cursor, srcA, valA, E);

    k_splitw<<<128, 256, 0, stream>>>(gc0_w, wt0h, wt0l, 512, 64, 64);
    k_splitw<<<16, 256, 0, stream>>>(gc1_w, wt1h, wt1l, 64, 64, 64);
    k_splitw<<<16, 256, 0, stream>>>(lin0_w, wl0h, wl0l, 64, 64, 64);
    k_splitw<<<16, 256, 0, stream>>>(lin1_w, wl1h, wl1l, 64, 64, 64);
    k_splitw<<<16, 256, 0, stream>>>(lin2_w, wl2h, wl2l, 64, 64, 64);
    k_splitw<<<8, 256, 0, stream>>>(lin3_w, wt3h, wt3l, 64, OUT_DIM, 32);

    // conv0
    k_gemm_mfma<IN_DIM, false, false><<<gT, 256, 0, stream>>>(x, wt0h, wt0l, nullptr, bufA, N);
    k_agg<<<gA, 256, 0, stream>>>(bufA, dinv, offar, srcA, valA, gc0_b, bufB, N);
    // conv1
    k_gemm_mfma<HG, false, false><<<gT, 256, 0, stream>>>(bufB, wt1h, wt1l, nullptr, bufA, N);
    k_agg<<<gA, 256, 0, stream>>>(bufA, dinv, offar, srcA, valA, gc1_b, bufB, N);
    // fused dense stack + softmax
    k_dense<<<gT, 256, 0, stream>>>(bufB,
                                    wl0h, wl0l, lin0_b,
                                    wl1h, wl1l, lin1_b,
                                    wl2h, wl2l, lin2_b,
                                    wt3h, wt3l, lin3_b,
                                    out, N);
}